// Round 1
// baseline (345.097 us; speedup 1.0000x reference)
//
#include <hip/hip_runtime.h>
#include <hip/hip_bf16.h>

#define NN 4096
#define INS 512
#define HIDW 512
#define MIDW 64
#define OUTW 128
#define CAP 384   // per-row nonzero capacity (mean ~205, +12 sigma < 280)

// ---------------------------------------------------------------------------
// K1: build row-padded CSR of a = adj*mask + I, plus rowsum; colsum via atomics
// ---------------------------------------------------------------------------
__global__ __launch_bounds__(256) void k_build(
    const float* __restrict__ adj, const float* __restrict__ xdeg,
    const float* __restrict__ ydeg,
    const float* __restrict__ w1, const float* __restrict__ b1,
    const float* __restrict__ w2, const float* __restrict__ b2,
    float* __restrict__ a_vals, int* __restrict__ a_cols, int* __restrict__ nnz,
    float* __restrict__ rowsum, float* __restrict__ colsum)
{
    __shared__ float sw1[48], sb1[16], sw2[32], sb2[2];
    __shared__ int   cnt;
    __shared__ float srs;
    const int t = threadIdx.x;
    if (t < 48) sw1[t] = w1[t];
    if (t < 16) sb1[t] = b1[t];
    if (t < 32) sw2[t] = w2[t];
    if (t < 2)  sb2[t] = b2[t];
    if (t == 0) { cnt = 0; srs = 0.f; }
    __syncthreads();

    const int i = blockIdx.x;
    const float* __restrict__ arow = adj + (size_t)i * NN;
    float local = 0.f;

    for (int jj = t; jj < NN; jj += 256) {
        float av = arow[jj];
        bool isd = (jj == i);
        if (av != 0.f || isd) {
            float v;
            if (av != 0.f) {
                float x = xdeg[(size_t)i * NN + jj];
                float y = ydeg[(size_t)i * NN + jj];
                float l0 = sb2[0], l1 = sb2[1];
                #pragma unroll
                for (int w = 0; w < 16; ++w) {
                    float hw = sb1[w];
                    hw = fmaf(av, sw1[w],      hw);
                    hw = fmaf(x,  sw1[16 + w], hw);
                    hw = fmaf(y,  sw1[32 + w], hw);
                    hw = fmaxf(hw, 0.f);
                    l0 = fmaf(hw, sw2[2 * w],     l0);
                    l1 = fmaf(hw, sw2[2 * w + 1], l1);
                }
                // softmax(...)[1] == sigmoid(l1 - l0)
                float m = 1.f / (1.f + expf(l0 - l1));
                v = av * m + (isd ? 1.f : 0.f);
            } else {
                v = 1.f;  // pure diagonal entry
            }
            int p = atomicAdd(&cnt, 1);
            if (p < CAP) {
                a_vals[(size_t)i * CAP + p] = v;
                a_cols[(size_t)i * CAP + p] = jj;
            }
            local += v;
            atomicAdd(&colsum[jj], v);
        }
    }
    atomicAdd(&srs, local);
    __syncthreads();
    if (t == 0) {
        nnz[i] = (cnt < CAP) ? cnt : CAP;
        rowsum[i] = srs;
    }
}

// ---------------------------------------------------------------------------
// K2: degree scale factors
// ---------------------------------------------------------------------------
__global__ void k_scale(const float* __restrict__ rowsum,
                        const float* __restrict__ colsum,
                        float* __restrict__ d_row, float* __restrict__ d_col)
{
    int i = blockIdx.x * blockDim.x + threadIdx.x;
    if (i < NN) {
        float r = rowsum[i];
        d_row[i] = (r > 0.f) ? 1.f / sqrtf(r) : 0.f;
        float c = colsum[i];
        d_col[i] = (c > 0.f) ? 1.f / sqrtf(c) : 0.f;
    }
}

// ---------------------------------------------------------------------------
// Generic fp32 tiled GEMM: C[M,Nn] = epi( (A(+abias,relu)) @ B )
// BM=BN=64, BK=16, 256 threads, 4x4 per thread
// ---------------------------------------------------------------------------
template <bool ABIAS, bool ARELU, bool NBIAS, bool ROWSCALE>
__global__ __launch_bounds__(256) void k_gemm(
    const float* __restrict__ A, const float* __restrict__ B,
    const float* __restrict__ abias, const float* __restrict__ nbias,
    const float* __restrict__ rscale, float* __restrict__ C,
    int M, int Nn, int K)
{
    const int BM = 64, BN = 64, BK = 16;
    __shared__ float As[BK][BM];
    __shared__ float Bs[BK][BN];
    const int tid = threadIdx.x;
    const int bm = blockIdx.x * BM;
    const int bn = blockIdx.y * BN;
    const int ty = tid / 16, tx = tid % 16;

    float acc[4][4] = {};

    for (int k0 = 0; k0 < K; k0 += BK) {
        #pragma unroll
        for (int l = 0; l < 4; ++l) {
            int e = tid + l * 256;
            int ar = e / BK, ak = e % BK;
            float v = A[(size_t)(bm + ar) * K + k0 + ak];
            if (ABIAS) v += abias[k0 + ak];
            if (ARELU) v = fmaxf(v, 0.f);
            As[ak][ar] = v;
        }
        #pragma unroll
        for (int l = 0; l < 4; ++l) {
            int e = tid + l * 256;
            int bk = e / BN, bnn = e % BN;
            Bs[bk][bnn] = B[(size_t)(k0 + bk) * Nn + bn + bnn];
        }
        __syncthreads();
        #pragma unroll
        for (int k = 0; k < BK; ++k) {
            float4 a4 = *reinterpret_cast<const float4*>(&As[k][ty * 4]);
            float4 b4 = *reinterpret_cast<const float4*>(&Bs[k][tx * 4]);
            const float aa[4] = {a4.x, a4.y, a4.z, a4.w};
            const float bb[4] = {b4.x, b4.y, b4.z, b4.w};
            #pragma unroll
            for (int u = 0; u < 4; ++u)
                #pragma unroll
                for (int v2 = 0; v2 < 4; ++v2)
                    acc[u][v2] = fmaf(aa[u], bb[v2], acc[u][v2]);
        }
        __syncthreads();
    }

    #pragma unroll
    for (int u = 0; u < 4; ++u) {
        int r = bm + ty * 4 + u;
        float rs = ROWSCALE ? rscale[r] : 1.f;
        float4 o;
        float* po = &o.x;
        #pragma unroll
        for (int v2 = 0; v2 < 4; ++v2) {
            int c = bn + tx * 4 + v2;
            float x = acc[u][v2] * rs;
            if (NBIAS) x += nbias[c];
            po[v2] = x;
        }
        *reinterpret_cast<float4*>(&C[(size_t)r * Nn + bn + tx * 4]) = o;
    }
}

// ---------------------------------------------------------------------------
// K4: SpMM width 512 + row-scale + BN1.  One block (256 thr) per row, 2 cols/thr
// ---------------------------------------------------------------------------
__global__ __launch_bounds__(256) void k_spmm512(
    const float* __restrict__ a_vals, const int* __restrict__ a_cols,
    const int* __restrict__ nnz, const float* __restrict__ X,
    const float* __restrict__ d_row,
    const float* __restrict__ bn_g, const float* __restrict__ bn_b,
    const float* __restrict__ bn_m, const float* __restrict__ bn_v,
    float* __restrict__ H)
{
    __shared__ float sv[256];
    __shared__ int   sc[256];
    const int i = blockIdx.x;
    const int t = threadIdx.x;
    const int n = nnz[i];
    const float* __restrict__ vrow = a_vals + (size_t)i * CAP;
    const int*   __restrict__ crow = a_cols + (size_t)i * CAP;

    float acc0 = 0.f, acc1 = 0.f;
    for (int base = 0; base < n; base += 256) {
        int m = min(256, n - base);
        __syncthreads();
        if (t < m) { sv[t] = vrow[base + t]; sc[t] = crow[base + t]; }
        __syncthreads();
        for (int q = 0; q < m; ++q) {
            float v = sv[q];
            const float* __restrict__ xr = X + (size_t)sc[q] * HIDW;
            acc0 = fmaf(v, xr[t],       acc0);
            acc1 = fmaf(v, xr[t + 256], acc1);
        }
    }
    float dr = d_row[i];
    {
        int c = t;
        float s = bn_g[c] / sqrtf(bn_v[c] + 1e-5f);
        H[(size_t)i * HIDW + c] = (acc0 * dr - bn_m[c]) * s + bn_b[c];
        c = t + 256;
        s = bn_g[c] / sqrtf(bn_v[c] + 1e-5f);
        H[(size_t)i * HIDW + c] = (acc1 * dr - bn_m[c]) * s + bn_b[c];
    }
}

// ---------------------------------------------------------------------------
// K7: SpMM width 128 + row-scale + BN2 -> final output.  128 thr per row.
// ---------------------------------------------------------------------------
__global__ __launch_bounds__(128) void k_spmm128(
    const float* __restrict__ a_vals, const int* __restrict__ a_cols,
    const int* __restrict__ nnz, const float* __restrict__ X,
    const float* __restrict__ d_row,
    const float* __restrict__ bn_g, const float* __restrict__ bn_b,
    const float* __restrict__ bn_m, const float* __restrict__ bn_v,
    float* __restrict__ out)
{
    __shared__ float sv[128];
    __shared__ int   sc[128];
    const int i = blockIdx.x;
    const int t = threadIdx.x;
    const int n = nnz[i];
    const float* __restrict__ vrow = a_vals + (size_t)i * CAP;
    const int*   __restrict__ crow = a_cols + (size_t)i * CAP;

    float acc = 0.f;
    for (int base = 0; base < n; base += 128) {
        int m = min(128, n - base);
        __syncthreads();
        if (t < m) { sv[t] = vrow[base + t]; sc[t] = crow[base + t]; }
        __syncthreads();
        for (int q = 0; q < m; ++q) {
            acc = fmaf(sv[q], X[(size_t)sc[q] * OUTW + t], acc);
        }
    }
    float dr = d_row[i];
    float s = bn_g[t] / sqrtf(bn_v[t] + 1e-5f);
    out[(size_t)i * OUTW + t] = (acc * dr - bn_m[t]) * s + bn_b[t];
}

// ---------------------------------------------------------------------------
extern "C" void kernel_launch(void* const* d_in, const int* in_sizes, int n_in,
                              void* d_out, int out_size, void* d_ws, size_t ws_size,
                              hipStream_t stream) {
    const float* adj    = (const float*)d_in[0];
    const float* xdeg   = (const float*)d_in[1];
    const float* ydeg   = (const float*)d_in[2];
    const float* mlp_w1 = (const float*)d_in[3];
    const float* mlp_b1 = (const float*)d_in[4];
    const float* mlp_w2 = (const float*)d_in[5];
    const float* mlp_b2 = (const float*)d_in[6];
    const float* pe_w   = (const float*)d_in[7];
    const float* pe_b   = (const float*)d_in[8];
    const float* gc1_w  = (const float*)d_in[9];
    const float* lin2_w = (const float*)d_in[10];
    const float* lin2_b = (const float*)d_in[11];
    const float* gc3_w  = (const float*)d_in[12];
    const float* bn1_g  = (const float*)d_in[13];
    const float* bn1_b  = (const float*)d_in[14];
    const float* bn1_m  = (const float*)d_in[15];
    const float* bn1_v  = (const float*)d_in[16];
    const float* bn2_g  = (const float*)d_in[17];
    const float* bn2_b  = (const float*)d_in[18];
    const float* bn2_m  = (const float*)d_in[19];
    const float* bn2_v  = (const float*)d_in[20];

    float* out = (float*)d_out;                 // [NN * OUTW]
    float* mid = out + (size_t)NN * OUTW;       // [NN * MIDW]

    char* w = (char*)d_ws;
    float* a_vals = (float*)w;  w += (size_t)NN * CAP * 4;
    int*   a_cols = (int*)w;    w += (size_t)NN * CAP * 4;
    int*   nnz    = (int*)w;    w += (size_t)NN * 4;
    float* rowsum = (float*)w;  w += (size_t)NN * 4;
    float* colsum = (float*)w;  w += (size_t)NN * 4;
    float* d_row  = (float*)w;  w += (size_t)NN * 4;
    float* d_col  = (float*)w;  w += (size_t)NN * 4;
    float* X1     = (float*)w;  w += (size_t)NN * HIDW * 4;
    float* H      = (float*)w;  w += (size_t)NN * HIDW * 4;
    float* X2     = (float*)w;  w += (size_t)NN * OUTW * 4;

    hipMemsetAsync(colsum, 0, NN * sizeof(float), stream);

    // 1) build sparse a, rowsum, colsum
    k_build<<<NN, 256, 0, stream>>>(adj, xdeg, ydeg, mlp_w1, mlp_b1, mlp_w2,
                                    mlp_b2, a_vals, a_cols, nnz, rowsum, colsum);
    // 2) scale factors
    k_scale<<<NN / 256, 256, 0, stream>>>(rowsum, colsum, d_row, d_col);
    // 3) X1 = d_col ⊙ ((pe_w + pe_b) @ gc1_w)     [4096,512]x[512,512]
    k_gemm<true, false, false, true><<<dim3(NN / 64, INS / 64), 256, 0, stream>>>(
        pe_w, gc1_w, pe_b, nullptr, d_col, X1, NN, HIDW, INS);
    // 4) H = BN1(d_row ⊙ (A @ X1))
    k_spmm512<<<NN, 256, 0, stream>>>(a_vals, a_cols, nnz, X1, d_row,
                                      bn1_g, bn1_b, bn1_m, bn1_v, H);
    // 5) mid = H @ lin2_w + lin2_b               [4096,512]x[512,64]
    k_gemm<false, false, true, false><<<dim3(NN / 64, MIDW / 64), 256, 0, stream>>>(
        H, lin2_w, nullptr, lin2_b, nullptr, mid, NN, MIDW, HIDW);
    // 6) X2 = d_col ⊙ (relu(mid) @ gc3_w)        [4096,64]x[64,128]
    k_gemm<false, true, false, true><<<dim3(NN / 64, OUTW / 64), 256, 0, stream>>>(
        mid, gc3_w, nullptr, nullptr, d_col, X2, NN, OUTW, MIDW);
    // 7) out = BN2(d_row ⊙ (A @ X2))
    k_spmm128<<<NN, 128, 0, stream>>>(a_vals, a_cols, nnz, X2, d_row,
                                      bn2_g, bn2_b, bn2_m, bn2_v, out);
}

// Round 3
// 309.180 us; speedup vs baseline: 1.1162x; 1.1162x over previous
//
#include <hip/hip_runtime.h>
#include <hip/hip_bf16.h>

#define NN 4096
#define INS 512
#define HIDW 512
#define MIDW 64
#define OUTW 128
#define CAP 384   // per-row nonzero capacity (mean ~205, binomial max ~275)

// ---------------------------------------------------------------------------
// K1: build row-padded CSR of a = adj*mask + I, plus rowsum; colsum via atomics
// Two-phase: (1) ballot-compact active columns into LDS, (2) dense MLP pass.
// adj is binary (0/1), so the adj-feature weight folds into the MLP bias.
// ---------------------------------------------------------------------------
__global__ __launch_bounds__(256) void k_build(
    const float* __restrict__ adj, const float* __restrict__ xdeg,
    const float* __restrict__ ydeg,
    const float* __restrict__ w1, const float* __restrict__ b1,
    const float* __restrict__ w2, const float* __restrict__ b2,
    float* __restrict__ a_vals, int* __restrict__ a_cols, int* __restrict__ nnz,
    float* __restrict__ rowsum, float* __restrict__ colsum)
{
    __shared__ float shb[16], sw1x[16], sw1y[16], sw2[32], sb2[2];
    __shared__ int   scols[CAP];
    __shared__ int   cnt_sh, diag_sh;
    __shared__ float srs;
    const int t = threadIdx.x;
    const int lane = t & 63;
    const int i = blockIdx.x;

    if (t < 16) {
        shb[t]  = b1[t] + w1[t];      // fold av==1 weight row into bias
        sw1x[t] = w1[16 + t];
        sw1y[t] = w1[32 + t];
    }
    if (t < 32) sw2[t] = w2[t];
    if (t < 2)  sb2[t] = b2[t];
    if (t == 0) { cnt_sh = 0; diag_sh = 0; srs = 0.f; }
    __syncthreads();

    const float* __restrict__ arow = adj + (size_t)i * NN;

    // ---- Phase 1: compact column indices of active entries into LDS ----
    for (int base = 0; base < NN; base += 1024) {
        float4 av4 = *reinterpret_cast<const float4*>(arow + base + 4 * t);
        const float avc[4] = {av4.x, av4.y, av4.z, av4.w};
        #pragma unroll
        for (int c = 0; c < 4; ++c) {
            int jj = base + 4 * t + c;
            bool nz = (avc[c] != 0.f);
            bool active = nz || (jj == i);
            if (nz && jj == i) diag_sh = 1;   // benign race, all write 1
            unsigned long long m = __ballot(active);
            int pos = __popcll(m & ((1ULL << lane) - 1));
            int wtotal = __popcll(m);
            int wbase = 0;
            if (lane == 0 && wtotal) wbase = atomicAdd(&cnt_sh, wtotal);
            wbase = __shfl(wbase, 0, 64);
            if (active) {
                int p = wbase + pos;
                if (p < CAP) scols[p] = jj;
            }
        }
    }
    __syncthreads();
    const int n = (cnt_sh < CAP) ? cnt_sh : CAP;
    const int has_diag_edge = diag_sh;

    // ---- Phase 2: dense MLP over compacted edges ----
    float local = 0.f;
    for (int p = t; p < n; p += 256) {
        int jj = scols[p];
        float v;
        if (jj == i && !has_diag_edge) {
            v = 1.f;   // pure inserted diagonal
        } else {
            float x = xdeg[(size_t)i * NN + jj];
            float y = ydeg[(size_t)i * NN + jj];
            float l0 = sb2[0], l1 = sb2[1];
            #pragma unroll
            for (int w = 0; w < 16; ++w) {
                float hw = fmaf(x, sw1x[w], shb[w]);
                hw = fmaf(y, sw1y[w], hw);
                hw = fmaxf(hw, 0.f);
                l0 = fmaf(hw, sw2[2 * w],     l0);
                l1 = fmaf(hw, sw2[2 * w + 1], l1);
            }
            // softmax(...)[1] == sigmoid(l1 - l0)
            v = 1.f / (1.f + __expf(l0 - l1));
            if (jj == i) v += 1.f;
        }
        a_cols[(size_t)i * CAP + p] = jj;
        a_vals[(size_t)i * CAP + p] = v;
        local += v;
        atomicAdd(&colsum[jj], v);
    }

    // wave reduce + one shared atomic per wave
    #pragma unroll
    for (int off = 32; off >= 1; off >>= 1)
        local += __shfl_down(local, off, 64);
    if (lane == 0) atomicAdd(&srs, local);
    __syncthreads();
    if (t == 0) {
        nnz[i] = n;
        rowsum[i] = srs;
    }
}

// ---------------------------------------------------------------------------
// K2: degree scale factors
// ---------------------------------------------------------------------------
__global__ void k_scale(const float* __restrict__ rowsum,
                        const float* __restrict__ colsum,
                        float* __restrict__ d_row, float* __restrict__ d_col)
{
    int i = blockIdx.x * blockDim.x + threadIdx.x;
    if (i < NN) {
        float r = rowsum[i];
        d_row[i] = (r > 0.f) ? 1.f / sqrtf(r) : 0.f;
        float c = colsum[i];
        d_col[i] = (c > 0.f) ? 1.f / sqrtf(c) : 0.f;
    }
}

// ---------------------------------------------------------------------------
// Generic fp32 tiled GEMM: C[M,Nn] = epi( (A(+abias,relu)) @ B )
// BM=BN=64, BK=16, 256 threads, 4x4 per thread
// ---------------------------------------------------------------------------
template <bool ABIAS, bool ARELU, bool NBIAS, bool ROWSCALE>
__global__ __launch_bounds__(256) void k_gemm(
    const float* __restrict__ A, const float* __restrict__ B,
    const float* __restrict__ abias, const float* __restrict__ nbias,
    const float* __restrict__ rscale, float* __restrict__ C,
    int M, int Nn, int K)
{
    const int BM = 64, BN = 64, BK = 16;
    __shared__ float As[BK][BM];
    __shared__ float Bs[BK][BN];
    const int tid = threadIdx.x;
    const int bm = blockIdx.x * BM;
    const int bn = blockIdx.y * BN;
    const int ty = tid / 16, tx = tid % 16;

    float acc[4][4] = {};

    for (int k0 = 0; k0 < K; k0 += BK) {
        #pragma unroll
        for (int l = 0; l < 4; ++l) {
            int e = tid + l * 256;
            int ar = e / BK, ak = e % BK;
            float v = A[(size_t)(bm + ar) * K + k0 + ak];
            if (ABIAS) v += abias[k0 + ak];
            if (ARELU) v = fmaxf(v, 0.f);
            As[ak][ar] = v;
        }
        #pragma unroll
        for (int l = 0; l < 4; ++l) {
            int e = tid + l * 256;
            int bk = e / BN, bnn = e % BN;
            Bs[bk][bnn] = B[(size_t)(k0 + bk) * Nn + bn + bnn];
        }
        __syncthreads();
        #pragma unroll
        for (int k = 0; k < BK; ++k) {
            float4 a4 = *reinterpret_cast<const float4*>(&As[k][ty * 4]);
            float4 b4 = *reinterpret_cast<const float4*>(&Bs[k][tx * 4]);
            const float aa[4] = {a4.x, a4.y, a4.z, a4.w};
            const float bb[4] = {b4.x, b4.y, b4.z, b4.w};
            #pragma unroll
            for (int u = 0; u < 4; ++u)
                #pragma unroll
                for (int v2 = 0; v2 < 4; ++v2)
                    acc[u][v2] = fmaf(aa[u], bb[v2], acc[u][v2]);
        }
        __syncthreads();
    }

    #pragma unroll
    for (int u = 0; u < 4; ++u) {
        int r = bm + ty * 4 + u;
        float rs = ROWSCALE ? rscale[r] : 1.f;
        float4 o;
        float* po = &o.x;
        #pragma unroll
        for (int v2 = 0; v2 < 4; ++v2) {
            int c = bn + tx * 4 + v2;
            float x = acc[u][v2] * rs;
            if (NBIAS) x += nbias[c];
            po[v2] = x;
        }
        *reinterpret_cast<float4*>(&C[(size_t)r * Nn + bn + tx * 4]) = o;
    }
}

// ---------------------------------------------------------------------------
// K4: SpMM width 512 + row-scale + BN1.  One block (256 thr) per row, 2 cols/thr
// ---------------------------------------------------------------------------
__global__ __launch_bounds__(256) void k_spmm512(
    const float* __restrict__ a_vals, const int* __restrict__ a_cols,
    const int* __restrict__ nnz, const float* __restrict__ X,
    const float* __restrict__ d_row,
    const float* __restrict__ bn_g, const float* __restrict__ bn_b,
    const float* __restrict__ bn_m, const float* __restrict__ bn_v,
    float* __restrict__ H)
{
    __shared__ float sv[256];
    __shared__ int   sc[256];
    const int i = blockIdx.x;
    const int t = threadIdx.x;
    const int n = nnz[i];
    const float* __restrict__ vrow = a_vals + (size_t)i * CAP;
    const int*   __restrict__ crow = a_cols + (size_t)i * CAP;

    float acc0 = 0.f, acc1 = 0.f;
    for (int base = 0; base < n; base += 256) {
        int m = min(256, n - base);
        __syncthreads();
        if (t < m) { sv[t] = vrow[base + t]; sc[t] = crow[base + t]; }
        __syncthreads();
        for (int q = 0; q < m; ++q) {
            float v = sv[q];
            const float* __restrict__ xr = X + (size_t)sc[q] * HIDW;
            acc0 = fmaf(v, xr[t],       acc0);
            acc1 = fmaf(v, xr[t + 256], acc1);
        }
    }
    float dr = d_row[i];
    {
        int c = t;
        float s = bn_g[c] / sqrtf(bn_v[c] + 1e-5f);
        H[(size_t)i * HIDW + c] = (acc0 * dr - bn_m[c]) * s + bn_b[c];
        c = t + 256;
        s = bn_g[c] / sqrtf(bn_v[c] + 1e-5f);
        H[(size_t)i * HIDW + c] = (acc1 * dr - bn_m[c]) * s + bn_b[c];
    }
}

// ---------------------------------------------------------------------------
// K7: SpMM width 128 + row-scale + BN2 -> final output.  128 thr per row.
// ---------------------------------------------------------------------------
__global__ __launch_bounds__(128) void k_spmm128(
    const float* __restrict__ a_vals, const int* __restrict__ a_cols,
    const int* __restrict__ nnz, const float* __restrict__ X,
    const float* __restrict__ d_row,
    const float* __restrict__ bn_g, const float* __restrict__ bn_b,
    const float* __restrict__ bn_m, const float* __restrict__ bn_v,
    float* __restrict__ out)
{
    __shared__ float sv[128];
    __shared__ int   sc[128];
    const int i = blockIdx.x;
    const int t = threadIdx.x;
    const int n = nnz[i];
    const float* __restrict__ vrow = a_vals + (size_t)i * CAP;
    const int*   __restrict__ crow = a_cols + (size_t)i * CAP;

    float acc = 0.f;
    for (int base = 0; base < n; base += 128) {
        int m = min(128, n - base);
        __syncthreads();
        if (t < m) { sv[t] = vrow[base + t]; sc[t] = crow[base + t]; }
        __syncthreads();
        for (int q = 0; q < m; ++q) {
            acc = fmaf(sv[q], X[(size_t)sc[q] * OUTW + t], acc);
        }
    }
    float dr = d_row[i];
    float s = bn_g[t] / sqrtf(bn_v[t] + 1e-5f);
    out[(size_t)i * OUTW + t] = (acc * dr - bn_m[t]) * s + bn_b[t];
}

// ---------------------------------------------------------------------------
extern "C" void kernel_launch(void* const* d_in, const int* in_sizes, int n_in,
                              void* d_out, int out_size, void* d_ws, size_t ws_size,
                              hipStream_t stream) {
    const float* adj    = (const float*)d_in[0];
    const float* xdeg   = (const float*)d_in[1];
    const float* ydeg   = (const float*)d_in[2];
    const float* mlp_w1 = (const float*)d_in[3];
    const float* mlp_b1 = (const float*)d_in[4];
    const float* mlp_w2 = (const float*)d_in[5];
    const float* mlp_b2 = (const float*)d_in[6];
    const float* pe_w   = (const float*)d_in[7];
    const float* pe_b   = (const float*)d_in[8];
    const float* gc1_w  = (const float*)d_in[9];
    const float* lin2_w = (const float*)d_in[10];
    const float* lin2_b = (const float*)d_in[11];
    const float* gc3_w  = (const float*)d_in[12];
    const float* bn1_g  = (const float*)d_in[13];
    const float* bn1_b  = (const float*)d_in[14];
    const float* bn1_m  = (const float*)d_in[15];
    const float* bn1_v  = (const float*)d_in[16];
    const float* bn2_g  = (const float*)d_in[17];
    const float* bn2_b  = (const float*)d_in[18];
    const float* bn2_m  = (const float*)d_in[19];
    const float* bn2_v  = (const float*)d_in[20];

    float* out = (float*)d_out;                 // [NN * OUTW]
    float* mid = out + (size_t)NN * OUTW;       // [NN * MIDW]

    char* w = (char*)d_ws;
    float* a_vals = (float*)w;  w += (size_t)NN * CAP * 4;
    int*   a_cols = (int*)w;    w += (size_t)NN * CAP * 4;
    int*   nnz    = (int*)w;    w += (size_t)NN * 4;
    float* rowsum = (float*)w;  w += (size_t)NN * 4;
    float* colsum = (float*)w;  w += (size_t)NN * 4;
    float* d_row  = (float*)w;  w += (size_t)NN * 4;
    float* d_col  = (float*)w;  w += (size_t)NN * 4;
    float* X1     = (float*)w;  w += (size_t)NN * HIDW * 4;
    float* H      = (float*)w;  w += (size_t)NN * HIDW * 4;
    float* X2     = (float*)w;  w += (size_t)NN * OUTW * 4;

    hipMemsetAsync(colsum, 0, NN * sizeof(float), stream);

    // 1) build sparse a, rowsum, colsum
    k_build<<<NN, 256, 0, stream>>>(adj, xdeg, ydeg, mlp_w1, mlp_b1, mlp_w2,
                                    mlp_b2, a_vals, a_cols, nnz, rowsum, colsum);
    // 2) scale factors
    k_scale<<<NN / 256, 256, 0, stream>>>(rowsum, colsum, d_row, d_col);
    // 3) X1 = d_col ⊙ ((pe_w + pe_b) @ gc1_w)     [4096,512]x[512,512]
    k_gemm<true, false, false, true><<<dim3(NN / 64, INS / 64), 256, 0, stream>>>(
        pe_w, gc1_w, pe_b, nullptr, d_col, X1, NN, HIDW, INS);
    // 4) H = BN1(d_row ⊙ (A @ X1))
    k_spmm512<<<NN, 256, 0, stream>>>(a_vals, a_cols, nnz, X1, d_row,
                                      bn1_g, bn1_b, bn1_m, bn1_v, H);
    // 5) mid = H @ lin2_w + lin2_b               [4096,512]x[512,64]
    k_gemm<false, false, true, false><<<dim3(NN / 64, MIDW / 64), 256, 0, stream>>>(
        H, lin2_w, nullptr, lin2_b, nullptr, mid, NN, MIDW, HIDW);
    // 6) X2 = d_col ⊙ (relu(mid) @ gc3_w)        [4096,64]x[64,128]
    k_gemm<false, true, false, true><<<dim3(NN / 64, OUTW / 64), 256, 0, stream>>>(
        mid, gc3_w, nullptr, nullptr, d_col, X2, NN, OUTW, MIDW);
    // 7) out = BN2(d_row ⊙ (A @ X2))
    k_spmm128<<<NN, 128, 0, stream>>>(a_vals, a_cols, nnz, X2, d_row,
                                      bn2_g, bn2_b, bn2_m, bn2_v, out);
}

// Round 4
// 303.151 us; speedup vs baseline: 1.1384x; 1.0199x over previous
//
#include <hip/hip_runtime.h>
#include <hip/hip_bf16.h>

#define NN 4096
#define INS 512
#define HIDW 512
#define MIDW 64
#define OUTW 128
#define CAP 384   // per-row nonzero capacity (mean ~205, binomial max ~275)

// ---------------------------------------------------------------------------
// K1: build row-padded CSR of a = adj*mask + I, plus rowsum; colsum via atomics
// Two-phase: (1) ballot-compact active columns into LDS, (2) dense MLP pass.
// adj is binary (0/1), so the adj-feature weight folds into the MLP bias.
// ---------------------------------------------------------------------------
__global__ __launch_bounds__(256) void k_build(
    const float* __restrict__ adj, const float* __restrict__ xdeg,
    const float* __restrict__ ydeg,
    const float* __restrict__ w1, const float* __restrict__ b1,
    const float* __restrict__ w2, const float* __restrict__ b2,
    float* __restrict__ a_vals, int* __restrict__ a_cols, int* __restrict__ nnz,
    float* __restrict__ rowsum, float* __restrict__ colsum)
{
    __shared__ float shb[16], sw1x[16], sw1y[16], sw2[32], sb2[2];
    __shared__ int   scols[CAP];
    __shared__ int   cnt_sh, diag_sh;
    __shared__ float srs;
    const int t = threadIdx.x;
    const int lane = t & 63;
    const int i = blockIdx.x;

    if (t < 16) {
        shb[t]  = b1[t] + w1[t];      // fold av==1 weight row into bias
        sw1x[t] = w1[16 + t];
        sw1y[t] = w1[32 + t];
    }
    if (t < 32) sw2[t] = w2[t];
    if (t < 2)  sb2[t] = b2[t];
    if (t == 0) { cnt_sh = 0; diag_sh = 0; srs = 0.f; }
    __syncthreads();

    const float* __restrict__ arow = adj + (size_t)i * NN;

    // ---- Phase 1: compact column indices of active entries into LDS ----
    for (int base = 0; base < NN; base += 1024) {
        float4 av4 = *reinterpret_cast<const float4*>(arow + base + 4 * t);
        const float avc[4] = {av4.x, av4.y, av4.z, av4.w};
        #pragma unroll
        for (int c = 0; c < 4; ++c) {
            int jj = base + 4 * t + c;
            bool nz = (avc[c] != 0.f);
            bool active = nz || (jj == i);
            if (nz && jj == i) diag_sh = 1;   // benign race, all write 1
            unsigned long long m = __ballot(active);
            int pos = __popcll(m & ((1ULL << lane) - 1));
            int wtotal = __popcll(m);
            int wbase = 0;
            if (lane == 0 && wtotal) wbase = atomicAdd(&cnt_sh, wtotal);
            wbase = __shfl(wbase, 0, 64);
            if (active) {
                int p = wbase + pos;
                if (p < CAP) scols[p] = jj;
            }
        }
    }
    __syncthreads();
    const int n = (cnt_sh < CAP) ? cnt_sh : CAP;
    const int has_diag_edge = diag_sh;

    // ---- Phase 2: dense MLP over compacted edges ----
    float local = 0.f;
    for (int p = t; p < n; p += 256) {
        int jj = scols[p];
        float v;
        if (jj == i && !has_diag_edge) {
            v = 1.f;   // pure inserted diagonal
        } else {
            float x = xdeg[(size_t)i * NN + jj];
            float y = ydeg[(size_t)i * NN + jj];
            float l0 = sb2[0], l1 = sb2[1];
            #pragma unroll
            for (int w = 0; w < 16; ++w) {
                float hw = fmaf(x, sw1x[w], shb[w]);
                hw = fmaf(y, sw1y[w], hw);
                hw = fmaxf(hw, 0.f);
                l0 = fmaf(hw, sw2[2 * w],     l0);
                l1 = fmaf(hw, sw2[2 * w + 1], l1);
            }
            // softmax(...)[1] == sigmoid(l1 - l0)
            v = 1.f / (1.f + __expf(l0 - l1));
            if (jj == i) v += 1.f;
        }
        a_cols[(size_t)i * CAP + p] = jj;
        a_vals[(size_t)i * CAP + p] = v;
        local += v;
        atomicAdd(&colsum[jj], v);
    }

    // wave reduce + one shared atomic per wave
    #pragma unroll
    for (int off = 32; off >= 1; off >>= 1)
        local += __shfl_down(local, off, 64);
    if (lane == 0) atomicAdd(&srs, local);
    __syncthreads();
    if (t == 0) {
        nnz[i] = n;
        rowsum[i] = srs;
    }
}

// ---------------------------------------------------------------------------
// K2: degree scale factors
// ---------------------------------------------------------------------------
__global__ void k_scale(const float* __restrict__ rowsum,
                        const float* __restrict__ colsum,
                        float* __restrict__ d_row, float* __restrict__ d_col)
{
    int i = blockIdx.x * blockDim.x + threadIdx.x;
    if (i < NN) {
        float r = rowsum[i];
        d_row[i] = (r > 0.f) ? 1.f / sqrtf(r) : 0.f;
        float c = colsum[i];
        d_col[i] = (c > 0.f) ? 1.f / sqrtf(c) : 0.f;
    }
}

// ---------------------------------------------------------------------------
// Generic fp32 tiled GEMM: C[M,Nn] = epi( (A(+abias,relu)) @ B )
// BM=BN=64, BK=16, 256 threads, 4x4 per thread
// ---------------------------------------------------------------------------
template <bool ABIAS, bool ARELU, bool NBIAS, bool ROWSCALE>
__global__ __launch_bounds__(256) void k_gemm(
    const float* __restrict__ A, const float* __restrict__ B,
    const float* __restrict__ abias, const float* __restrict__ nbias,
    const float* __restrict__ rscale, float* __restrict__ C,
    int M, int Nn, int K)
{
    const int BM = 64, BN = 64, BK = 16;
    __shared__ float As[BK][BM];
    __shared__ float Bs[BK][BN];
    const int tid = threadIdx.x;
    const int bm = blockIdx.x * BM;
    const int bn = blockIdx.y * BN;
    const int ty = tid / 16, tx = tid % 16;

    float acc[4][4] = {};

    for (int k0 = 0; k0 < K; k0 += BK) {
        #pragma unroll
        for (int l = 0; l < 4; ++l) {
            int e = tid + l * 256;
            int ar = e / BK, ak = e % BK;
            float v = A[(size_t)(bm + ar) * K + k0 + ak];
            if (ABIAS) v += abias[k0 + ak];
            if (ARELU) v = fmaxf(v, 0.f);
            As[ak][ar] = v;
        }
        #pragma unroll
        for (int l = 0; l < 4; ++l) {
            int e = tid + l * 256;
            int bk = e / BN, bnn = e % BN;
            Bs[bk][bnn] = B[(size_t)(k0 + bk) * Nn + bn + bnn];
        }
        __syncthreads();
        #pragma unroll
        for (int k = 0; k < BK; ++k) {
            float4 a4 = *reinterpret_cast<const float4*>(&As[k][ty * 4]);
            float4 b4 = *reinterpret_cast<const float4*>(&Bs[k][tx * 4]);
            const float aa[4] = {a4.x, a4.y, a4.z, a4.w};
            const float bb[4] = {b4.x, b4.y, b4.z, b4.w};
            #pragma unroll
            for (int u = 0; u < 4; ++u)
                #pragma unroll
                for (int v2 = 0; v2 < 4; ++v2)
                    acc[u][v2] = fmaf(aa[u], bb[v2], acc[u][v2]);
        }
        __syncthreads();
    }

    #pragma unroll
    for (int u = 0; u < 4; ++u) {
        int r = bm + ty * 4 + u;
        float rs = ROWSCALE ? rscale[r] : 1.f;
        float4 o;
        float* po = &o.x;
        #pragma unroll
        for (int v2 = 0; v2 < 4; ++v2) {
            int c = bn + tx * 4 + v2;
            float x = acc[u][v2] * rs;
            if (NBIAS) x += nbias[c];
            po[v2] = x;
        }
        *reinterpret_cast<float4*>(&C[(size_t)r * Nn + bn + tx * 4]) = o;
    }
}

// ---------------------------------------------------------------------------
// SpMM (column-chunked): Y[i, c0:c0+128] = BN(d_row[i] * sum_p a[i,p]*X[col_p, c0:...])
// One block per (row, chunk); chunk = blockIdx.y is the SLOW grid index so the
// in-flight block window shares one 2 MB X-chunk -> per-XCD L2 resident.
// 4 waves split the edge list; each lane covers 2 cols via float2 gathers.
// ---------------------------------------------------------------------------
#define SPMM_CHUNK 128
__global__ __launch_bounds__(256) void k_spmm(
    const float* __restrict__ a_vals, const int* __restrict__ a_cols,
    const int* __restrict__ nnz, const float* __restrict__ X, int ldx,
    const float* __restrict__ d_row,
    const float* __restrict__ bn_g, const float* __restrict__ bn_b,
    const float* __restrict__ bn_m, const float* __restrict__ bn_v,
    float* __restrict__ Y, int ldy)
{
    __shared__ float sv[CAP];
    __shared__ int   scl[CAP];
    __shared__ float sacc[4][SPMM_CHUNK];
    const int i  = blockIdx.x;
    const int c0 = blockIdx.y * SPMM_CHUNK;
    const int t = threadIdx.x;
    const int wave = t >> 6, lane = t & 63;
    const int n = nnz[i];
    const float* __restrict__ vrow = a_vals + (size_t)i * CAP;
    const int*   __restrict__ crow = a_cols + (size_t)i * CAP;

    for (int p = t; p < n; p += 256) { sv[p] = vrow[p]; scl[p] = crow[p]; }
    __syncthreads();

    const float* __restrict__ Xc = X + c0 + 2 * lane;
    float a0 = 0.f, a1 = 0.f;
    int p = wave;
    // 4 edges in flight per wave
    for (; p + 12 < n; p += 16) {
        float v0 = sv[p];      float2 x0 = *(const float2*)(Xc + (size_t)scl[p]      * ldx);
        float v1 = sv[p + 4];  float2 x1 = *(const float2*)(Xc + (size_t)scl[p + 4]  * ldx);
        float v2 = sv[p + 8];  float2 x2 = *(const float2*)(Xc + (size_t)scl[p + 8]  * ldx);
        float v3 = sv[p + 12]; float2 x3 = *(const float2*)(Xc + (size_t)scl[p + 12] * ldx);
        a0 = fmaf(v0, x0.x, a0); a1 = fmaf(v0, x0.y, a1);
        a0 = fmaf(v1, x1.x, a0); a1 = fmaf(v1, x1.y, a1);
        a0 = fmaf(v2, x2.x, a0); a1 = fmaf(v2, x2.y, a1);
        a0 = fmaf(v3, x3.x, a0); a1 = fmaf(v3, x3.y, a1);
    }
    for (; p < n; p += 4) {
        float v = sv[p];
        float2 x = *(const float2*)(Xc + (size_t)scl[p] * ldx);
        a0 = fmaf(v, x.x, a0); a1 = fmaf(v, x.y, a1);
    }
    sacc[wave][2 * lane]     = a0;
    sacc[wave][2 * lane + 1] = a1;
    __syncthreads();

    if (t < SPMM_CHUNK) {
        float s = sacc[0][t] + sacc[1][t] + sacc[2][t] + sacc[3][t];
        int c = c0 + t;
        float dr = d_row[i];
        float bs = bn_g[c] / sqrtf(bn_v[c] + 1e-5f);
        Y[(size_t)i * ldy + c] = (s * dr - bn_m[c]) * bs + bn_b[c];
    }
}

// ---------------------------------------------------------------------------
extern "C" void kernel_launch(void* const* d_in, const int* in_sizes, int n_in,
                              void* d_out, int out_size, void* d_ws, size_t ws_size,
                              hipStream_t stream) {
    const float* adj    = (const float*)d_in[0];
    const float* xdeg   = (const float*)d_in[1];
    const float* ydeg   = (const float*)d_in[2];
    const float* mlp_w1 = (const float*)d_in[3];
    const float* mlp_b1 = (const float*)d_in[4];
    const float* mlp_w2 = (const float*)d_in[5];
    const float* mlp_b2 = (const float*)d_in[6];
    const float* pe_w   = (const float*)d_in[7];
    const float* pe_b   = (const float*)d_in[8];
    const float* gc1_w  = (const float*)d_in[9];
    const float* lin2_w = (const float*)d_in[10];
    const float* lin2_b = (const float*)d_in[11];
    const float* gc3_w  = (const float*)d_in[12];
    const float* bn1_g  = (const float*)d_in[13];
    const float* bn1_b  = (const float*)d_in[14];
    const float* bn1_m  = (const float*)d_in[15];
    const float* bn1_v  = (const float*)d_in[16];
    const float* bn2_g  = (const float*)d_in[17];
    const float* bn2_b  = (const float*)d_in[18];
    const float* bn2_m  = (const float*)d_in[19];
    const float* bn2_v  = (const float*)d_in[20];

    float* out = (float*)d_out;                 // [NN * OUTW]
    float* mid = out + (size_t)NN * OUTW;       // [NN * MIDW]

    char* w = (char*)d_ws;
    float* a_vals = (float*)w;  w += (size_t)NN * CAP * 4;
    int*   a_cols = (int*)w;    w += (size_t)NN * CAP * 4;
    int*   nnz    = (int*)w;    w += (size_t)NN * 4;
    float* rowsum = (float*)w;  w += (size_t)NN * 4;
    float* colsum = (float*)w;  w += (size_t)NN * 4;
    float* d_row  = (float*)w;  w += (size_t)NN * 4;
    float* d_col  = (float*)w;  w += (size_t)NN * 4;
    float* X1     = (float*)w;  w += (size_t)NN * HIDW * 4;
    float* H      = (float*)w;  w += (size_t)NN * HIDW * 4;
    float* X2     = (float*)w;  w += (size_t)NN * OUTW * 4;

    hipMemsetAsync(colsum, 0, NN * sizeof(float), stream);

    // 1) build sparse a, rowsum, colsum
    k_build<<<NN, 256, 0, stream>>>(adj, xdeg, ydeg, mlp_w1, mlp_b1, mlp_w2,
                                    mlp_b2, a_vals, a_cols, nnz, rowsum, colsum);
    // 2) scale factors
    k_scale<<<NN / 256, 256, 0, stream>>>(rowsum, colsum, d_row, d_col);
    // 3) X1 = d_col ⊙ ((pe_w + pe_b) @ gc1_w)     [4096,512]x[512,512]
    k_gemm<true, false, false, true><<<dim3(NN / 64, INS / 64), 256, 0, stream>>>(
        pe_w, gc1_w, pe_b, nullptr, d_col, X1, NN, HIDW, INS);
    // 4) H = BN1(d_row ⊙ (A @ X1))   — column-chunked SpMM, 4 chunks of 128
    k_spmm<<<dim3(NN, HIDW / SPMM_CHUNK), 256, 0, stream>>>(
        a_vals, a_cols, nnz, X1, HIDW, d_row, bn1_g, bn1_b, bn1_m, bn1_v, H, HIDW);
    // 5) mid = H @ lin2_w + lin2_b               [4096,512]x[512,64]
    k_gemm<false, false, true, false><<<dim3(NN / 64, MIDW / 64), 256, 0, stream>>>(
        H, lin2_w, nullptr, lin2_b, nullptr, mid, NN, MIDW, HIDW);
    // 6) X2 = d_col ⊙ (relu(mid) @ gc3_w)        [4096,64]x[64,128]
    k_gemm<false, true, false, true><<<dim3(NN / 64, OUTW / 64), 256, 0, stream>>>(
        mid, gc3_w, nullptr, nullptr, d_col, X2, NN, OUTW, MIDW);
    // 7) out = BN2(d_row ⊙ (A @ X2))  — single chunk (X2 is 2 MB, L2-resident)
    k_spmm<<<dim3(NN, OUTW / SPMM_CHUNK), 256, 0, stream>>>(
        a_vals, a_cols, nnz, X2, OUTW, d_row, bn2_g, bn2_b, bn2_m, bn2_v, out, OUTW);
}

// Round 5
// 175.611 us; speedup vs baseline: 1.9651x; 1.7263x over previous
//
#include <hip/hip_runtime.h>
#include <hip/hip_bf16.h>

#define NN 4096
#define INS 512
#define HIDW 512
#define MIDW 64
#define OUTW 128
#define CAP 384   // per-row nonzero capacity (mean ~205, binomial max ~275)
#define BN_EPS 1e-5f

// ---------------------------------------------------------------------------
// K1: build row-padded CSR of a = adj*mask + I, plus rowsum; colsum via atomics
// ---------------------------------------------------------------------------
__global__ __launch_bounds__(256) void k_build(
    const float* __restrict__ adj, const float* __restrict__ xdeg,
    const float* __restrict__ ydeg,
    const float* __restrict__ w1, const float* __restrict__ b1,
    const float* __restrict__ w2, const float* __restrict__ b2,
    float* __restrict__ a_vals, int* __restrict__ a_cols, int* __restrict__ nnz,
    float* __restrict__ rowsum, float* __restrict__ colsum)
{
    __shared__ float shb[16], sw1x[16], sw1y[16], sw2[32], sb2[2];
    __shared__ int   scols[CAP];
    __shared__ int   cnt_sh, diag_sh;
    __shared__ float srs;
    const int t = threadIdx.x;
    const int lane = t & 63;
    const int i = blockIdx.x;

    if (t < 16) {
        shb[t]  = b1[t] + w1[t];      // fold av==1 weight row into bias
        sw1x[t] = w1[16 + t];
        sw1y[t] = w1[32 + t];
    }
    if (t < 32) sw2[t] = w2[t];
    if (t < 2)  sb2[t] = b2[t];
    if (t == 0) { cnt_sh = 0; diag_sh = 0; srs = 0.f; }
    __syncthreads();

    const float* __restrict__ arow = adj + (size_t)i * NN;

    for (int base = 0; base < NN; base += 1024) {
        float4 av4 = *reinterpret_cast<const float4*>(arow + base + 4 * t);
        const float avc[4] = {av4.x, av4.y, av4.z, av4.w};
        #pragma unroll
        for (int c = 0; c < 4; ++c) {
            int jj = base + 4 * t + c;
            bool nz = (avc[c] != 0.f);
            bool active = nz || (jj == i);
            if (nz && jj == i) diag_sh = 1;
            unsigned long long m = __ballot(active);
            int pos = __popcll(m & ((1ULL << lane) - 1));
            int wtotal = __popcll(m);
            int wbase = 0;
            if (lane == 0 && wtotal) wbase = atomicAdd(&cnt_sh, wtotal);
            wbase = __shfl(wbase, 0, 64);
            if (active) {
                int p = wbase + pos;
                if (p < CAP) scols[p] = jj;
            }
        }
    }
    __syncthreads();
    const int n = (cnt_sh < CAP) ? cnt_sh : CAP;
    const int has_diag_edge = diag_sh;

    float local = 0.f;
    for (int p = t; p < n; p += 256) {
        int jj = scols[p];
        float v;
        if (jj == i && !has_diag_edge) {
            v = 1.f;
        } else {
            float x = xdeg[(size_t)i * NN + jj];
            float y = ydeg[(size_t)i * NN + jj];
            float l0 = sb2[0], l1 = sb2[1];
            #pragma unroll
            for (int w = 0; w < 16; ++w) {
                float hw = fmaf(x, sw1x[w], shb[w]);
                hw = fmaf(y, sw1y[w], hw);
                hw = fmaxf(hw, 0.f);
                l0 = fmaf(hw, sw2[2 * w],     l0);
                l1 = fmaf(hw, sw2[2 * w + 1], l1);
            }
            v = 1.f / (1.f + __expf(l0 - l1));
            if (jj == i) v += 1.f;
        }
        a_cols[(size_t)i * CAP + p] = jj;
        a_vals[(size_t)i * CAP + p] = v;
        local += v;
        atomicAdd(&colsum[jj], v);
    }

    #pragma unroll
    for (int off = 32; off >= 1; off >>= 1)
        local += __shfl_down(local, off, 64);
    if (lane == 0) atomicAdd(&srs, local);
    __syncthreads();
    if (t == 0) {
        nnz[i] = n;
        rowsum[i] = srs;
    }
}

// ---------------------------------------------------------------------------
// K2: degree scale factors
// ---------------------------------------------------------------------------
__global__ void k_scale(const float* __restrict__ rowsum,
                        const float* __restrict__ colsum,
                        float* __restrict__ d_row, float* __restrict__ d_col)
{
    int i = blockIdx.x * blockDim.x + threadIdx.x;
    if (i < NN) {
        float r = rowsum[i];
        d_row[i] = (r > 0.f) ? 1.f / sqrtf(r) : 0.f;
        float c = colsum[i];
        d_col[i] = (c > 0.f) ? 1.f / sqrtf(c) : 0.f;
    }
}

// ---------------------------------------------------------------------------
// K3: prep — Wp = s1 ⊙rows lin2_w ;  c1 = t1@lin2_w + lin2_b ;  s2/t2 for BN2
// s1 = bn1_g/sqrt(bn1_v+eps), t1 = bn1_b - bn1_m*s1
// ---------------------------------------------------------------------------
__global__ __launch_bounds__(512) void k_prep(
    const float* __restrict__ lin2_w, const float* __restrict__ lin2_b,
    const float* __restrict__ bn1_g, const float* __restrict__ bn1_b,
    const float* __restrict__ bn1_m, const float* __restrict__ bn1_v,
    const float* __restrict__ bn2_g, const float* __restrict__ bn2_b,
    const float* __restrict__ bn2_m, const float* __restrict__ bn2_v,
    float* __restrict__ Wp, float* __restrict__ c1,
    float* __restrict__ s2g, float* __restrict__ t2g)
{
    __shared__ float t1s[HIDW];
    const int t = threadIdx.x;
    // phase a: per-h scale/shift + Wp
    {
        int h = t;
        float s1 = bn1_g[h] * rsqrtf(bn1_v[h] + BN_EPS);
        t1s[h] = bn1_b[h] - bn1_m[h] * s1;
        for (int m = 0; m < MIDW; ++m)
            Wp[(size_t)h * MIDW + m] = s1 * lin2_w[(size_t)h * MIDW + m];
    }
    __syncthreads();
    if (t < MIDW) {
        float acc = lin2_b[t];
        for (int h = 0; h < HIDW; ++h)
            acc = fmaf(t1s[h], lin2_w[(size_t)h * MIDW + t], acc);
        c1[t] = acc;
    } else if (t >= 64 && t < 64 + OUTW) {
        int j = t - 64;
        float s2 = bn2_g[j] * rsqrtf(bn2_v[j] + BN_EPS);
        s2g[j] = s2;
        t2g[j] = bn2_b[j] - bn2_m[j] * s2;
    }
}

// ---------------------------------------------------------------------------
// K4: thin GEMM  C[M x 64] = (A[M x K] (+abias along k)) @ B[K x 64], epi rowscale
// 256 threads, RB=16 rows/block, K staged in chunks of 64.
// ---------------------------------------------------------------------------
template <bool ABIAS, bool ROWSCALE>
__global__ __launch_bounds__(256) void k_thin(
    const float* __restrict__ A, const float* __restrict__ B,
    const float* __restrict__ abias, const float* __restrict__ rscale,
    float* __restrict__ C, int M, int K)
{
    __shared__ float As[64][20];   // [k][r], stride 20 -> b128-aligned reads
    __shared__ float Bs[64][64];
    const int t = threadIdx.x;
    const int bm = blockIdx.x * 16;
    const int col = t & 63, rg = t >> 6;   // rg*4 .. rg*4+3 rows

    float acc[4] = {0.f, 0.f, 0.f, 0.f};

    for (int k0 = 0; k0 < K; k0 += 64) {
        #pragma unroll
        for (int l = 0; l < 4; ++l) {
            int e = t + l * 256;          // 1024 elems
            int r = e >> 6, k = e & 63;
            float v = A[(size_t)(bm + r) * K + k0 + k];
            if (ABIAS) v += abias[k0 + k];
            As[k][r] = v;
        }
        #pragma unroll
        for (int l = 0; l < 16; ++l) {
            int e = t + l * 256;          // 4096 elems
            int k = e >> 6, n = e & 63;
            Bs[k][n] = B[(size_t)(k0 + k) * 64 + n];
        }
        __syncthreads();
        #pragma unroll
        for (int k = 0; k < 64; ++k) {
            float4 a4 = *reinterpret_cast<const float4*>(&As[k][rg * 4]);
            float b = Bs[k][col];
            acc[0] = fmaf(a4.x, b, acc[0]);
            acc[1] = fmaf(a4.y, b, acc[1]);
            acc[2] = fmaf(a4.z, b, acc[2]);
            acc[3] = fmaf(a4.w, b, acc[3]);
        }
        __syncthreads();
    }

    #pragma unroll
    for (int u = 0; u < 4; ++u) {
        int r = bm + rg * 4 + u;
        float x = acc[u];
        if (ROWSCALE) x *= rscale[r];
        C[(size_t)r * 64 + col] = x;
    }
}

// ---------------------------------------------------------------------------
// K5: 64-wide SpMM, 1 wave per row, 2 edges per load-inst (512 B/inst).
// WITH_MID: mid = dr*acc + c1 (output), R = dc*relu(mid)   (two outputs)
// else:     S = dr*acc
// ---------------------------------------------------------------------------
template <bool WITH_MID>
__global__ __launch_bounds__(64) void k_spmm64(
    const float* __restrict__ a_vals, const int* __restrict__ a_cols,
    const int* __restrict__ nnz, const float* __restrict__ X,
    const float* __restrict__ d_row, const float* __restrict__ d_col,
    const float* __restrict__ c1,
    float* __restrict__ O1, float* __restrict__ O2)
{
    __shared__ float sv[CAP];
    __shared__ int   scl[CAP];
    const int i = blockIdx.x;
    const int lane = threadIdx.x;
    const int n = nnz[i];
    const int n8 = (n + 7) & ~7;
    const float* __restrict__ vrow = a_vals + (size_t)i * CAP;
    const int*   __restrict__ crow = a_cols + (size_t)i * CAP;

    for (int p = lane; p < n8; p += 64) {
        bool ok = p < n;
        sv[p]  = ok ? vrow[p] : 0.f;
        scl[p] = ok ? crow[p] : 0;
    }
    __syncthreads();

    const int eh = lane >> 5;          // which edge of the pair
    const int lc = lane & 31;          // col pair index: cols 2lc, 2lc+1
    const int npairs = n8 >> 1;

    float a0 = 0.f, a1 = 0.f;
    for (int q = 0; q < npairs; q += 4) {
        #pragma unroll
        for (int j = 0; j < 4; ++j) {
            int p = 2 * (q + j) + eh;
            float v = sv[p];
            int c = scl[p];
            float2 x = *reinterpret_cast<const float2*>(X + (size_t)c * 64 + 2 * lc);
            a0 = fmaf(v, x.x, a0);
            a1 = fmaf(v, x.y, a1);
        }
    }
    a0 += __shfl_xor(a0, 32);
    a1 += __shfl_xor(a1, 32);

    if (lane < 32) {
        float dr = d_row[i];
        if (WITH_MID) {
            float dc = d_col[i];
            float m0 = fmaf(a0, dr, c1[2 * lc]);
            float m1 = fmaf(a1, dr, c1[2 * lc + 1]);
            *reinterpret_cast<float2*>(O1 + (size_t)i * 64 + 2 * lc) =
                make_float2(m0, m1);
            *reinterpret_cast<float2*>(O2 + (size_t)i * 64 + 2 * lc) =
                make_float2(dc * fmaxf(m0, 0.f), dc * fmaxf(m1, 0.f));
        } else {
            *reinterpret_cast<float2*>(O1 + (size_t)i * 64 + 2 * lc) =
                make_float2(a0 * dr, a1 * dr);
        }
    }
}

// ---------------------------------------------------------------------------
// K6: out[4096x128] = (S[4096x64] @ gc3[64x128]) * s2 + t2
// 256 threads, 16 rows/block; gc3 fully staged in LDS.
// ---------------------------------------------------------------------------
__global__ __launch_bounds__(256) void k_out(
    const float* __restrict__ S, const float* __restrict__ gc3,
    const float* __restrict__ s2g, const float* __restrict__ t2g,
    float* __restrict__ out)
{
    __shared__ float Ss[64][20];       // [k][r]
    __shared__ float Gs[64][128];
    const int t = threadIdx.x;
    const int bm = blockIdx.x * 16;

    {   // stage S tile transposed: thread reads float4 of one row
        int r = t >> 4, c4 = (t & 15) * 4;
        float4 v = *reinterpret_cast<const float4*>(S + (size_t)(bm + r) * 64 + c4);
        Ss[c4 + 0][r] = v.x; Ss[c4 + 1][r] = v.y;
        Ss[c4 + 2][r] = v.z; Ss[c4 + 3][r] = v.w;
    }
    #pragma unroll
    for (int l = 0; l < 32; ++l) {
        int e = t + l * 256;           // 8192 elems
        Gs[e >> 7][e & 127] = gc3[e];
    }
    __syncthreads();

    const int j = t & 127;
    const int r0 = (t >> 7) * 8;       // 8 rows per thread
    float acc[8] = {};
    #pragma unroll
    for (int k = 0; k < 64; ++k) {
        float g = Gs[k][j];
        float4 a = *reinterpret_cast<const float4*>(&Ss[k][r0]);
        float4 b = *reinterpret_cast<const float4*>(&Ss[k][r0 + 4]);
        acc[0] = fmaf(a.x, g, acc[0]); acc[1] = fmaf(a.y, g, acc[1]);
        acc[2] = fmaf(a.z, g, acc[2]); acc[3] = fmaf(a.w, g, acc[3]);
        acc[4] = fmaf(b.x, g, acc[4]); acc[5] = fmaf(b.y, g, acc[5]);
        acc[6] = fmaf(b.z, g, acc[6]); acc[7] = fmaf(b.w, g, acc[7]);
    }
    float s2 = s2g[j], t2 = t2g[j];
    #pragma unroll
    for (int u = 0; u < 8; ++u)
        out[(size_t)(bm + r0 + u) * 128 + j] = fmaf(acc[u], s2, t2);
}

// ---------------------------------------------------------------------------
extern "C" void kernel_launch(void* const* d_in, const int* in_sizes, int n_in,
                              void* d_out, int out_size, void* d_ws, size_t ws_size,
                              hipStream_t stream) {
    const float* adj    = (const float*)d_in[0];
    const float* xdeg   = (const float*)d_in[1];
    const float* ydeg   = (const float*)d_in[2];
    const float* mlp_w1 = (const float*)d_in[3];
    const float* mlp_b1 = (const float*)d_in[4];
    const float* mlp_w2 = (const float*)d_in[5];
    const float* mlp_b2 = (const float*)d_in[6];
    const float* pe_w   = (const float*)d_in[7];
    const float* pe_b   = (const float*)d_in[8];
    const float* gc1_w  = (const float*)d_in[9];
    const float* lin2_w = (const float*)d_in[10];
    const float* lin2_b = (const float*)d_in[11];
    const float* gc3_w  = (const float*)d_in[12];
    const float* bn1_g  = (const float*)d_in[13];
    const float* bn1_b  = (const float*)d_in[14];
    const float* bn1_m  = (const float*)d_in[15];
    const float* bn1_v  = (const float*)d_in[16];
    const float* bn2_g  = (const float*)d_in[17];
    const float* bn2_b  = (const float*)d_in[18];
    const float* bn2_m  = (const float*)d_in[19];
    const float* bn2_v  = (const float*)d_in[20];

    float* out = (float*)d_out;                 // [NN * OUTW]
    float* mid = out + (size_t)NN * OUTW;       // [NN * MIDW]

    char* w = (char*)d_ws;
    float* a_vals = (float*)w;  w += (size_t)NN * CAP * 4;
    int*   a_cols = (int*)w;    w += (size_t)NN * CAP * 4;
    int*   nnz    = (int*)w;    w += (size_t)NN * 4;
    float* rowsum = (float*)w;  w += (size_t)NN * 4;
    float* colsum = (float*)w;  w += (size_t)NN * 4;
    float* d_row  = (float*)w;  w += (size_t)NN * 4;
    float* d_col  = (float*)w;  w += (size_t)NN * 4;
    float* Wp     = (float*)w;  w += (size_t)HIDW * MIDW * 4;
    float* W2     = (float*)w;  w += (size_t)INS * MIDW * 4;
    float* c1     = (float*)w;  w += 256;
    float* s2g    = (float*)w;  w += 512;
    float* t2g    = (float*)w;  w += 512;
    float* G      = (float*)w;  w += (size_t)NN * MIDW * 4;
    float* R      = (float*)w;  w += (size_t)NN * MIDW * 4;
    float* S      = (float*)w;  w += (size_t)NN * MIDW * 4;

    hipMemsetAsync(colsum, 0, NN * sizeof(float), stream);

    // 1) sparse a, rowsum, colsum
    k_build<<<NN, 256, 0, stream>>>(adj, xdeg, ydeg, mlp_w1, mlp_b1, mlp_w2,
                                    mlp_b2, a_vals, a_cols, nnz, rowsum, colsum);
    // 2) degree scales
    k_scale<<<NN / 256, 256, 0, stream>>>(rowsum, colsum, d_row, d_col);
    // 3) BN-fold precompute: Wp = s1⊙lin2, c1, s2/t2
    k_prep<<<1, 512, 0, stream>>>(lin2_w, lin2_b, bn1_g, bn1_b, bn1_m, bn1_v,
                                  bn2_g, bn2_b, bn2_m, bn2_v, Wp, c1, s2g, t2g);
    // 4) W2 = gc1 @ Wp                      [512x512]@[512x64]
    k_thin<false, false><<<INS / 16, 256, 0, stream>>>(
        gc1_w, Wp, nullptr, nullptr, W2, INS, HIDW);
    // 5) G = d_col ⊙ ((pe_w + pe_b) @ W2)   [4096x512]@[512x64]
    k_thin<true, true><<<NN / 16, 256, 0, stream>>>(
        pe_w, W2, pe_b, d_col, G, NN, INS);
    // 6) mid = Dr·(Â@G) + c1 ; R = d_col ⊙ relu(mid)
    k_spmm64<true><<<NN, 64, 0, stream>>>(
        a_vals, a_cols, nnz, G, d_row, d_col, c1, mid, R);
    // 7) S = Dr·(Â@R)
    k_spmm64<false><<<NN, 64, 0, stream>>>(
        a_vals, a_cols, nnz, R, d_row, d_col, nullptr, S, nullptr);
    // 8) out = BN2(S @ gc3)
    k_out<<<NN / 16, 256, 0, stream>>>(S, gc3_w, s2g, t2g, out);
}